// Round 17
// baseline (57.592 us; speedup 1.0000x reference)
//
#include <hip/hip_runtime.h>

// Two-level connected components, fused output. (r16 base; Phase A rebuilt:
// float4 loads + LDS nibble assembly replaces per-row ballot+scalar init.)
//  - cc_local (256 thr): per-tile union-find in LDS.
//    Phase A: each thread loads 4 float4s (vs 16 scalar), stages 4-bit fg
//    nibbles as bytes in LDS (aliasing lp's first 1KB), 64 threads pack
//    nibbles -> 64-bit row masks, then init writes lp as int4 (run-start
//    parents computed from the row mask in registers).
//    Vertical edges: edge-owner threads (row = t&63, type = t>>6) derive
//    edge masks from wave-uniform row masks and merge run starts.
//    Border roots flagged in lp bit 16; Phase C root walk picks the flag
//    up for free and appends flagged pixels to a per-tile worklist.
//  - cc_border_bm: cross-tile merges; fg tests from a 2MB bitmap,
//    union-find on the sparse parent (endpoints = strip pixels + roots).
//  - cc_fixup: walks worklist entries only (~1.5% of pixels), rewrites
//    labels whose root changed.
//
// Label semantics: out = MULT - min(local linear index over 8-conn component)
// for foreground, 0 for background.
//
// UF invariant: parent[v] <= v, every stored value is a true ancestor ->
// atomicMin linking converges to exact min-index roots (verified r1-r16).
// lp encoding: low 16 bits = parent (0..4095); bit 16 = border flag, set
// ONLY on final roots (after the edge barrier, before Phase C).

constexpr int W_DIM = 2048;
constexpr int H_DIM = 2048;
constexpr int MULT  = W_DIM * H_DIM;        // 2^22 pixels per image
constexpr int TILE  = 64;
constexpr int TPX   = TILE * TILE;          // 4096 pixels per tile
constexpr int BLK   = 256;
constexpr int TILES_PER_IMG = MULT / TPX;   // 1024
constexpr int NB    = (H_DIM / TILE) - 1;   // 31 interior boundaries per dim
constexpr int WCAP  = 512;                  // per-tile worklist capacity
constexpr int OVF_CAP = 65536;              // global overflow capacity
constexpr int PMASK = 0xFFFF;               // lp parent field
constexpr int BFLAG = 0x10000;              // lp border flag (roots only)

__device__ __forceinline__ int find_root(const int* p, int v) {
    int q = p[v];
    while (q != v) { v = q; q = p[v]; }
    return v;
}

// flag-tolerant find (marking pass: flags may appear concurrently on roots)
__device__ __forceinline__ int find_root_m(const int* p, int v) {
    int q = p[v] & PMASK;
    while (q != v) { v = q; q = p[v] & PMASK; }
    return v;
}

__device__ __forceinline__ void merge_uf(int* p, int a, int b) {
    while (true) {
        a = find_root(p, a);
        b = find_root(p, b);
        if (a == b) return;
        if (a < b) { int t = a; a = b; b = t; }  // a > b
        int old = atomicMin(&p[a], b);
        if (old == a) return;                    // a was root; linked under b
        a = old;                                 // displaced; retry from old
    }
}

// pack 4 nibbles (at bits 0-3,8-11,16-19,24-27 of a dword) into bits 0-15
__device__ __forceinline__ unsigned pack16(unsigned v) {
    v &= 0x0F0F0F0Fu;
    v = (v | (v >> 4)) & 0x00FF00FFu;
    v = (v | (v >> 8)) & 0x0000FFFFu;
    return v;
}

// MODE 0: legacy (write full parent). MODE 1: fused (write out + sparse UF).
template <int MODE>
__global__ __launch_bounds__(BLK) void cc_local(const float* __restrict__ x,
                                                int* __restrict__ parent,
                                                float* __restrict__ out,
                                                unsigned long long* __restrict__ bitmap,
                                                int2* __restrict__ slabs,
                                                int* __restrict__ wl_cnt,
                                                int2* __restrict__ ovf,
                                                int* __restrict__ ovf_cnt) {
    __shared__ int lp[TPX];
    __shared__ unsigned long long rowmask_sh[TILE];
    __shared__ int cursor;

    const int t    = threadIdx.x;
    const int wave = t >> 6;                 // 0..3
    const int lane = t & 63;
    const int tile = blockIdx.x;
    const int img  = tile / TILES_PER_IMG;
    const int tl   = tile % TILES_PER_IMG;
    const int tr   = tl >> 5;                // 32 tile cols per image row
    const int tc   = tl & 31;
    const int origin    = img * MULT + (tr * TILE) * W_DIM + tc * TILE;
    const int img_base  = img * MULT;
    const int base_loc  = origin - img_base; // tile origin, local-in-image

    // ---- Phase A1: float4 loads -> fg nibbles staged in LDS (alias lp) ----
    char* nib = (char*)lp;                   // first 1KB of lp, pre-init
    #pragma unroll
    for (int j = 0; j < 4; ++j) {
        int s   = t + BLK * j;               // float4 slot in tile
        int row = s >> 4;                    // 16 slots per 64-px row
        int c4  = s & 15;
        float4 xv = reinterpret_cast<const float4*>(x + origin + row * W_DIM)[c4];
        int nb = (int)(xv.x != 0.f) | ((int)(xv.y != 0.f) << 1)
               | ((int)(xv.z != 0.f) << 2) | ((int)(xv.w != 0.f) << 3);
        nib[s] = (char)nb;
    }
    if constexpr (MODE == 1) {
        if (t == 0) cursor = 0;
    }
    __syncthreads();

    // ---- Phase A2: 64 threads pack 16 nibbles -> 64-bit row mask ----
    if (t < TILE) {
        int4 q = reinterpret_cast<const int4*>(nib)[t];   // row t's nibbles
        unsigned long long m0 = pack16((unsigned)q.x);
        unsigned long long m1 = pack16((unsigned)q.y);
        unsigned long long m2 = pack16((unsigned)q.z);
        unsigned long long m3 = pack16((unsigned)q.w);
        rowmask_sh[t] = m0 | (m1 << 16) | (m2 << 32) | (m3 << 48);
    }
    __syncthreads();

    // ---- Phase A3: run-start lp init, int4 writes (4 px/iter per thread) ----
    #pragma unroll
    for (int j = 0; j < 4; ++j) {
        int s   = t + BLK * j;
        int row = s >> 4;
        int c4  = s & 15;
        unsigned long long mm = rowmask_sh[row];          // broadcast read
        int rbase = row * TILE;
        int4 o;
        #pragma unroll
        for (int k = 0; k < 4; ++k) {
            int idx = c4 * 4 + k;
            unsigned long long below = ~mm & ((1ULL << idx) - 1ULL);
            int start = below ? (64 - __clzll(below)) : 0;
            bool fg = (mm >> idx) & 1ULL;
            int val = rbase + (fg ? start : idx);
            if (k == 0) o.x = val; else if (k == 1) o.y = val;
            else if (k == 2) o.z = val; else o.w = val;
        }
        reinterpret_cast<int4*>(lp)[s] = o;
    }

    // bitmap export: one wave-wide store (lane = row), masks from LDS.
    if constexpr (MODE == 1) {
        if (wave == 0) {
            int grow = tr * TILE + lane;
            bitmap[(img * H_DIM + grow) * (W_DIM / 64) + tc] = rowmask_sh[lane];
        }
    }
    __syncthreads();

    // ---- Edge phase: thread t owns (row = t&63, type = t>>6).
    // Types: 0 = bf cols 0-31, 1 = bf cols 32-63, 2 = af, 3 = cf.
    // Edge masks are the verified suppression algebra (r3-r16):
    //   bf = mm & mu & ~((mm<<1)&(mu<<1));  af = mm & (mu<<1) & ~mu & ~(mm<<1);
    //   cf = mm & (mu>>1) & ~mu.
    // Each set bit c: merge run-start(row,c) with run-start(row-1,c+dx).
    {
        int row  = t & 63;
        int slot = t >> 6;
        if (row > 0) {
            const unsigned long long mm = rowmask_sh[row];
            const unsigned long long mu = rowmask_sh[row - 1];
            unsigned long long em;
            int dx;
            if (slot == 0)      { em = (mm & mu & ~((mm << 1) & (mu << 1))) & 0xFFFFFFFFULL;  dx = 0; }
            else if (slot == 1) { em = (mm & mu & ~((mm << 1) & (mu << 1))) & ~0xFFFFFFFFULL; dx = 0; }
            else if (slot == 2) { em = mm & (mu << 1) & ~mu & ~(mm << 1);                     dx = -1; }
            else                { em = mm & (mu >> 1) & ~mu;                                  dx = 1; }
            while (em) {
                int c = (int)__builtin_ctzll(em);
                em &= em - 1;
                unsigned long long below  = ~mm & ((1ULL << c) - 1ULL);
                int sp = below ? (64 - __clzll(below)) : 0;
                int cu = c + dx;
                unsigned long long belowu = ~mu & ((1ULL << cu) - 1ULL);
                int su = belowu ? (64 - __clzll(belowu)) : 0;
                merge_uf(lp, row * TILE + sp, (row - 1) * TILE + su);
            }
        }
    }
    __syncthreads();

    // ---- Marking (MODE 1): wave-parallel strip marking. Flag the root in
    // lp (bit 16) and seed the sparse global parent (pixel + root). ----
    if constexpr (MODE == 1) {
        int p = -1;
        bool mark = false;
        if      (wave == 0) { if (tr > 0)  { p = lane;                      mark = (rowmask_sh[0]    >> lane) & 1ULL; } }
        else if (wave == 3) { if (tr < 31) { p = (TILE - 1) * TILE + lane;  mark = (rowmask_sh[63]   >> lane) & 1ULL; } }
        else if (wave == 1) { if (tc > 0)  { p = lane * TILE;               mark = rowmask_sh[lane] & 1ULL; } }
        else                { if (tc < 31) { p = lane * TILE + (TILE - 1);  mark = (rowmask_sh[lane] >> 63) & 1ULL; } }
        if (mark) {
            int v = find_root_m(lp, p);
            atomicOr(&lp[v], BFLAG);
            int rg = origin + (v >> 6) * W_DIM + (v & (TILE - 1));
            int pg = origin + (p >> 6) * W_DIM + (p & (TILE - 1));
            parent[pg] = rg;
            parent[rg] = rg;
        }
        __syncthreads();
    }

    // ---- Phase C: root walk (flag rides the final read), write labels
    // (MODE1) or parent (MODE0); flagged pixels append inline. ----
    #pragma unroll
    for (int j = 0; j < 4; ++j) {
        int s   = t + BLK * j;               // int4 slot in tile
        int row = s >> 4;
        int c4  = s & 15;
        int p0  = row * TILE + c4 * 4;
        int4 qv = reinterpret_cast<const int4*>(lp)[s];
        unsigned fgbits = (unsigned)((rowmask_sh[row] >> (c4 * 4)) & 0xFULL);
        int vr[4], qf[4];
        {
            int q = qv.x, v = q & PMASK, p = p0;
            if ((fgbits & 1u) && v != p) {
                int w = lp[v];
                while ((w & PMASK) != v) { v = w & PMASK; w = lp[v]; }
                q = w;
            }
            vr[0] = v; qf[0] = q;
        }
        {
            int q = qv.y, v = q & PMASK, p = p0 + 1;
            if ((fgbits & 2u) && v != p) {
                int w = lp[v];
                while ((w & PMASK) != v) { v = w & PMASK; w = lp[v]; }
                q = w;
            }
            vr[1] = v; qf[1] = q;
        }
        {
            int q = qv.z, v = q & PMASK, p = p0 + 2;
            if ((fgbits & 4u) && v != p) {
                int w = lp[v];
                while ((w & PMASK) != v) { v = w & PMASK; w = lp[v]; }
                q = w;
            }
            vr[2] = v; qf[2] = q;
        }
        {
            int q = qv.w, v = q & PMASK, p = p0 + 3;
            if ((fgbits & 8u) && v != p) {
                int w = lp[v];
                while ((w & PMASK) != v) { v = w & PMASK; w = lp[v]; }
                q = w;
            }
            vr[3] = v; qf[3] = q;
        }

        if constexpr (MODE == 0) {
            int4 o;
            o.x = (fgbits & 1u) ? origin + (vr[0] >> 6) * W_DIM + (vr[0] & (TILE - 1)) : -1;
            o.y = (fgbits & 2u) ? origin + (vr[1] >> 6) * W_DIM + (vr[1] & (TILE - 1)) : -1;
            o.z = (fgbits & 4u) ? origin + (vr[2] >> 6) * W_DIM + (vr[2] & (TILE - 1)) : -1;
            o.w = (fgbits & 8u) ? origin + (vr[3] >> 6) * W_DIM + (vr[3] & (TILE - 1)) : -1;
            reinterpret_cast<int4*>(parent + origin + row * W_DIM)[c4] = o;
        } else {
            float lab[4];
            #pragma unroll
            for (int k = 0; k < 4; ++k) {
                int v  = vr[k];
                bool fg = (fgbits >> k) & 1u;
                int rl = base_loc + ((v >> 6) << 11) + (v & (TILE - 1)); // root, local-in-image
                lab[k] = fg ? (float)(MULT - rl) : 0.0f;
                if (fg && (qf[k] & BFLAG)) {                 // border component
                    int off = atomicAdd(&cursor, 1);
                    int pg  = origin + row * W_DIM + c4 * 4 + k;
                    int g   = img_base + rl;
                    if (off < WCAP) slabs[tile * WCAP + off] = make_int2(pg, g);
                    else {
                        int oi = atomicAdd(ovf_cnt, 1);
                        if (oi < OVF_CAP) ovf[oi] = make_int2(pg, g);
                    }
                }
            }
            float4 o; o.x = lab[0]; o.y = lab[1]; o.z = lab[2]; o.w = lab[3];
            reinterpret_cast<float4*>(out + origin + row * W_DIM)[c4] = o;
        }
    }

    if constexpr (MODE == 1) {
        __syncthreads();
        if (t == 0) wl_cnt[tile] = (cursor < WCAP) ? cursor : WCAP;
    }
}

// Cross-tile merges; fg from bitmap, UF on sparse parent (endpoints are
// strip pixels -> initialized by cc_local's marking pass).
__global__ __launch_bounds__(BLK) void cc_border_bm(const unsigned long long* __restrict__ bm,
                                                    int* __restrict__ parent, int total) {
    int tid = blockIdx.x * blockDim.x + threadIdx.x;
    if (tid >= total) return;
    const int per_img = 2 * NB * W_DIM;
    int img = tid / per_img;
    int k   = tid % per_img;
    int base = img * MULT;
    const unsigned long long* b = bm + (size_t)img * H_DIM * (W_DIM / 64);
    auto FG = [&](int r, int c) -> bool {
        return (b[r * (W_DIM / 64) + (c >> 6)] >> (c & 63)) & 1ULL;
    };
    if (k < NB * W_DIM) {
        int r = TILE * (1 + k / W_DIM);
        int c = k % W_DIM;
        if (!FG(r, c)) return;
        int i  = base + r * W_DIM + c;
        int up = i - W_DIM;
        if (FG(r - 1, c))                      merge_uf(parent, i, up);
        if (c > 0         && FG(r - 1, c - 1)) merge_uf(parent, i, up - 1);
        if (c < W_DIM - 1 && FG(r - 1, c + 1)) merge_uf(parent, i, up + 1);
    } else {
        int m2 = k - NB * W_DIM;
        int c = TILE * (1 + m2 / H_DIM);
        int r = m2 % H_DIM;
        if (!FG(r, c)) return;
        int i   = base + r * W_DIM + c;
        int lft = i - 1;
        if (FG(r, c - 1))                      merge_uf(parent, i, lft);
        if (r > 0         && FG(r - 1, c - 1)) merge_uf(parent, i, lft - W_DIM);
        if (r < H_DIM - 1 && FG(r + 1, c - 1)) merge_uf(parent, i, lft + W_DIM);
    }
}

// Rewrite labels of border-component pixels whose root changed.
__global__ __launch_bounds__(BLK) void cc_fixup(const int2* __restrict__ slabs,
                                                const int* __restrict__ wl_cnt,
                                                const int2* __restrict__ ovf,
                                                const int* __restrict__ ovf_cnt,
                                                const int* __restrict__ parent,
                                                float* __restrict__ out, int ntiles) {
    int tid = blockIdx.x * blockDim.x + threadIdx.x;
    int slab_total = ntiles * WCAP;
    int2 e;
    if (tid < slab_total) {
        int tile = tid / WCAP, slot = tid - tile * WCAP;
        if (slot >= wl_cnt[tile]) return;
        e = slabs[tid];
    } else {
        int oi = tid - slab_total;
        int oc = *ovf_cnt; if (oc > OVF_CAP) oc = OVF_CAP;
        if (oi >= oc) return;
        e = ovf[oi];
    }
    int root = find_root(parent, e.y);
    if (root != e.y) out[e.x] = (float)(MULT - (root & (MULT - 1)));
}

// ---------------- legacy fallback kernels ----------------
__global__ __launch_bounds__(BLK) void cc_border(int* __restrict__ parent, int total) {
    int tid = blockIdx.x * blockDim.x + threadIdx.x;
    if (tid >= total) return;
    const int per_img = 2 * NB * W_DIM;
    int img = tid / per_img;
    int k   = tid % per_img;
    int base = img * MULT;
    if (k < NB * W_DIM) {
        int r = TILE * (1 + k / W_DIM);
        int c = k % W_DIM;
        int i = base + r * W_DIM + c;
        if (parent[i] < 0) return;
        int up = i - W_DIM;
        if (parent[up] >= 0)                      merge_uf(parent, i, up);
        if (c > 0         && parent[up - 1] >= 0) merge_uf(parent, i, up - 1);
        if (c < W_DIM - 1 && parent[up + 1] >= 0) merge_uf(parent, i, up + 1);
    } else {
        int m2 = k - NB * W_DIM;
        int c = TILE * (1 + m2 / H_DIM);
        int r = m2 % H_DIM;
        int i = base + r * W_DIM + c;
        if (parent[i] < 0) return;
        int lft = i - 1;
        if (parent[lft] >= 0)                            merge_uf(parent, i, lft);
        if (r > 0         && parent[lft - W_DIM] >= 0)   merge_uf(parent, i, lft - W_DIM);
        if (r < H_DIM - 1 && parent[lft + W_DIM] >= 0)   merge_uf(parent, i, lft + W_DIM);
    }
}

__global__ __launch_bounds__(BLK) void cc_write(const int* __restrict__ parent,
                                                float* __restrict__ out, int n4) {
    int i = blockIdx.x * blockDim.x + threadIdx.x;
    if (i >= n4) return;
    int4 p = reinterpret_cast<const int4*>(parent)[i];
    int a0 = (p.x >= 0) ? parent[p.x] : 0;
    int a1 = (p.y >= 0) ? parent[p.y] : 0;
    int a2 = (p.z >= 0) ? parent[p.z] : 0;
    int a3 = (p.w >= 0) ? parent[p.w] : 0;
    float4 o;
    { int v = p.x, w = a0; if (v >= 0) { while (w != v) { v = w; w = parent[v]; } }
      o.x = (p.x < 0) ? 0.f : (float)(MULT - (v & (MULT - 1))); }
    { int v = p.y, w = a1; if (v >= 0) { while (w != v) { v = w; w = parent[v]; } }
      o.y = (p.y < 0) ? 0.f : (float)(MULT - (v & (MULT - 1))); }
    { int v = p.z, w = a2; if (v >= 0) { while (w != v) { v = w; w = parent[v]; } }
      o.z = (p.z < 0) ? 0.f : (float)(MULT - (v & (MULT - 1))); }
    { int v = p.w, w = a3; if (v >= 0) { while (w != v) { v = w; w = parent[v]; } }
      o.w = (p.w < 0) ? 0.f : (float)(MULT - (v & (MULT - 1))); }
    reinterpret_cast<float4*>(out)[i] = o;
}

__global__ __launch_bounds__(BLK) void cc_flatten(int* __restrict__ parent, int n) {
    int i = blockIdx.x * blockDim.x + threadIdx.x;
    if (i >= n) return;
    int p = parent[i];
    if (p < 0 || p == i) return;
    int r = find_root(parent, p);
    if (r != p) parent[i] = r;
}

__global__ __launch_bounds__(BLK) void cc_final_inplace(int* __restrict__ parent, int n4) {
    int i = blockIdx.x * blockDim.x + threadIdx.x;
    if (i >= n4) return;
    int4 p = reinterpret_cast<const int4*>(parent)[i];
    float4 o;
    o.x = (p.x < 0) ? 0.f : (float)(MULT - (p.x & (MULT - 1)));
    o.y = (p.y < 0) ? 0.f : (float)(MULT - (p.y & (MULT - 1)));
    o.z = (p.z < 0) ? 0.f : (float)(MULT - (p.z & (MULT - 1)));
    o.w = (p.w < 0) ? 0.f : (float)(MULT - (p.w & (MULT - 1)));
    reinterpret_cast<float4*>(parent)[i] = o;
}

extern "C" void kernel_launch(void* const* d_in, const int* in_sizes, int n_in,
                              void* d_out, int out_size, void* d_ws, size_t ws_size,
                              hipStream_t stream) {
    const float* x = (const float*)d_in[0];
    const int n     = in_sizes[0];          // B*H*W
    const int n_img = n / MULT;
    const int n4    = n / 4;
    const int tiles = n_img * TILES_PER_IMG;
    const int border_threads = n_img * 2 * NB * W_DIM;

    // fused-path workspace layout
    size_t off_parent = 0;
    size_t off_bitmap = off_parent + (size_t)n * 4;
    size_t off_slabs  = off_bitmap + (size_t)n / 8;
    size_t off_cnt    = off_slabs  + (size_t)tiles * WCAP * 8;
    size_t off_ovf    = off_cnt    + (size_t)tiles * 4;
    size_t off_ovfcnt = off_ovf    + (size_t)OVF_CAP * 8;
    size_t need_fused = off_ovfcnt + 128;

    if (ws_size >= need_fused) {
        char* ws = (char*)d_ws;
        int*  parent  = (int*)(ws + off_parent);
        unsigned long long* bitmap = (unsigned long long*)(ws + off_bitmap);
        int2* slabs   = (int2*)(ws + off_slabs);
        int*  wl_cnt  = (int*)(ws + off_cnt);
        int2* ovf     = (int2*)(ws + off_ovf);
        int*  ovf_cnt = (int*)(ws + off_ovfcnt);
        float* out    = (float*)d_out;

        hipMemsetAsync(ovf_cnt, 0, sizeof(int), stream);
        cc_local<1><<<tiles, BLK, 0, stream>>>(x, parent, out, bitmap,
                                               slabs, wl_cnt, ovf, ovf_cnt);
        cc_border_bm<<<(border_threads + BLK - 1) / BLK, BLK, 0, stream>>>(bitmap, parent, border_threads);
        int fix_threads = tiles * WCAP + OVF_CAP;
        cc_fixup<<<(fix_threads + BLK - 1) / BLK, BLK, 0, stream>>>(slabs, wl_cnt, ovf, ovf_cnt,
                                                                    parent, out, tiles);
    } else {
        const bool use_ws = (ws_size >= (size_t)n * sizeof(int));
        int* parent = use_ws ? (int*)d_ws : (int*)d_out;
        cc_local<0><<<tiles, BLK, 0, stream>>>(x, parent, nullptr, nullptr,
                                               nullptr, nullptr, nullptr, nullptr);
        cc_border<<<(border_threads + BLK - 1) / BLK, BLK, 0, stream>>>(parent, border_threads);
        if (use_ws) {
            cc_write<<<(n4 + BLK - 1) / BLK, BLK, 0, stream>>>(parent, (float*)d_out, n4);
        } else {
            cc_flatten      <<<(n + BLK - 1) / BLK, BLK, 0, stream>>>(parent, n);
            cc_final_inplace<<<(n4 + BLK - 1) / BLK, BLK, 0, stream>>>(parent, n4);
        }
    }
}

// Round 18
// 56.877 us; speedup vs baseline: 1.0126x; 1.0126x over previous
//
#include <hip/hip_runtime.h>

// Two-level connected components, fused output. (FINAL — round-14/16
// configuration, best measured: 56.9 us timed, 3.6x over the round-1
// global union-find baseline, ~2.7x above the 21 us pure-traffic floor;
// remaining gap is the per-tile UF dependent-LDS critical path, which
// five structural attempts (r10-r17) could not compress further.)
//  - cc_local (256 thr): per-tile union-find in LDS. lp init = per-row run
//    starts. Vertical edges handled by EDGE-OWNER threads: thread t owns
//    (row = t&63, type = t>>6 in {bf-lo, bf-hi, af, cf}); it derives its edge
//    mask from two wave-uniform row masks in LDS (~8 VALU) and serially
//    merges its set bits, with both endpoints' run starts computed in
//    registers. Border roots flagged in lp bit 16; Phase C root walk picks
//    the flag up for free and appends flagged pixels to a per-tile worklist.
//  - cc_border_bm: cross-tile merges; fg tests from a 2MB bitmap,
//    union-find on the sparse parent (endpoints = strip pixels + roots).
//  - cc_fixup: walks worklist entries only (~1.5% of pixels), rewrites
//    labels whose root changed.
//
// Label semantics: out = MULT - min(local linear index over 8-conn component)
// for foreground, 0 for background.
//
// UF invariant: parent[v] <= v, every stored value is a true ancestor ->
// atomicMin linking converges to exact min-index roots (verified r1-r17).
// Edge-owner merges use union(start(p), start(up)) == union(p, up) since a
// run start is in the same component as every pixel of its run (init links).
// lp encoding: low 16 bits = parent (0..4095); bit 16 = border flag, set
// ONLY on final roots (after the edge barrier, before Phase C).

constexpr int W_DIM = 2048;
constexpr int H_DIM = 2048;
constexpr int MULT  = W_DIM * H_DIM;        // 2^22 pixels per image
constexpr int TILE  = 64;
constexpr int TPX   = TILE * TILE;          // 4096 pixels per tile
constexpr int BLK   = 256;
constexpr int TILES_PER_IMG = MULT / TPX;   // 1024
constexpr int NB    = (H_DIM / TILE) - 1;   // 31 interior boundaries per dim
constexpr int WCAP  = 512;                  // per-tile worklist capacity
constexpr int OVF_CAP = 65536;              // global overflow capacity
constexpr int PMASK = 0xFFFF;               // lp parent field
constexpr int BFLAG = 0x10000;              // lp border flag (roots only)

__device__ __forceinline__ int find_root(const int* p, int v) {
    int q = p[v];
    while (q != v) { v = q; q = p[v]; }
    return v;
}

// flag-tolerant find (marking pass: flags may appear concurrently on roots)
__device__ __forceinline__ int find_root_m(const int* p, int v) {
    int q = p[v] & PMASK;
    while (q != v) { v = q; q = p[v] & PMASK; }
    return v;
}

__device__ __forceinline__ void merge_uf(int* p, int a, int b) {
    while (true) {
        a = find_root(p, a);
        b = find_root(p, b);
        if (a == b) return;
        if (a < b) { int t = a; a = b; b = t; }  // a > b
        int old = atomicMin(&p[a], b);
        if (old == a) return;                    // a was root; linked under b
        a = old;                                 // displaced; retry from old
    }
}

// MODE 0: legacy (write full parent). MODE 1: fused (write out + sparse UF).
template <int MODE>
__global__ __launch_bounds__(BLK) void cc_local(const float* __restrict__ x,
                                                int* __restrict__ parent,
                                                float* __restrict__ out,
                                                unsigned long long* __restrict__ bitmap,
                                                int2* __restrict__ slabs,
                                                int* __restrict__ wl_cnt,
                                                int2* __restrict__ ovf,
                                                int* __restrict__ ovf_cnt) {
    __shared__ int lp[TPX];
    __shared__ unsigned long long rowmask_sh[TILE];
    __shared__ int cursor;

    const int t    = threadIdx.x;
    const int wave = t >> 6;                 // 0..3
    const int lane = t & 63;
    const int tile = blockIdx.x;
    const int img  = tile / TILES_PER_IMG;
    const int tl   = tile % TILES_PER_IMG;
    const int tr   = tl >> 5;                // 32 tile cols per image row
    const int tc   = tl & 31;
    const int origin    = img * MULT + (tr * TILE) * W_DIM + tc * TILE;
    const int img_base  = img * MULT;
    const int base_loc  = origin - img_base; // tile origin, local-in-image

    // ---- Phase A: load x, ballot row bitmaps, run-start lp init ----
    unsigned long long m[16];
    #pragma unroll
    for (int rr = 0; rr < 16; ++rr) {
        int row = wave * 16 + rr;
        float v = x[origin + row * W_DIM + lane];
        m[rr] = __ballot(v != 0.0f);
    }
    const unsigned long long lanebit_m1 = (1ULL << lane) - 1ULL;
    #pragma unroll
    for (int rr = 0; rr < 16; ++rr) {
        int row = wave * 16 + rr;
        unsigned long long mm = m[rr];
        unsigned long long below = ~mm & lanebit_m1;   // bg positions below lane
        int start = below ? (64 - __clzll(below)) : 0; // run start for fg pixels
        bool fg = (mm >> lane) & 1ULL;
        lp[row * TILE + lane] = row * TILE + (fg ? start : lane);
    }
    if (lane == 0) {
        #pragma unroll
        for (int rr = 0; rr < 16; ++rr) rowmask_sh[wave * 16 + rr] = m[rr];
    }
    if constexpr (MODE == 1) {
        if (t == 0) cursor = 0;
    }
    __syncthreads();

    // bitmap export: one wave-wide store (lane = row), masks from LDS.
    if constexpr (MODE == 1) {
        if (wave == 0) {
            int grow = tr * TILE + lane;
            bitmap[(img * H_DIM + grow) * (W_DIM / 64) + tc] = rowmask_sh[lane];
        }
    }

    // ---- Edge phase: thread t owns (row = t&63, type = t>>6).
    // Types: 0 = bf cols 0-31, 1 = bf cols 32-63, 2 = af, 3 = cf.
    // Edge masks are the verified suppression algebra (r3-r17):
    //   bf = mm & mu & ~((mm<<1)&(mu<<1));  af = mm & (mu<<1) & ~mu & ~(mm<<1);
    //   cf = mm & (mu>>1) & ~mu.
    // Each set bit c: merge run-start(row,c) with run-start(row-1,c+dx).
    {
        int row  = t & 63;
        int slot = t >> 6;
        if (row > 0) {
            const unsigned long long mm = rowmask_sh[row];
            const unsigned long long mu = rowmask_sh[row - 1];
            unsigned long long em;
            int dx;
            if (slot == 0)      { em = (mm & mu & ~((mm << 1) & (mu << 1))) & 0xFFFFFFFFULL;  dx = 0; }
            else if (slot == 1) { em = (mm & mu & ~((mm << 1) & (mu << 1))) & ~0xFFFFFFFFULL; dx = 0; }
            else if (slot == 2) { em = mm & (mu << 1) & ~mu & ~(mm << 1);                     dx = -1; }
            else                { em = mm & (mu >> 1) & ~mu;                                  dx = 1; }
            while (em) {
                int c = (int)__builtin_ctzll(em);
                em &= em - 1;
                unsigned long long below  = ~mm & ((1ULL << c) - 1ULL);
                int sp = below ? (64 - __clzll(below)) : 0;
                int cu = c + dx;
                unsigned long long belowu = ~mu & ((1ULL << cu) - 1ULL);
                int su = belowu ? (64 - __clzll(belowu)) : 0;
                merge_uf(lp, row * TILE + sp, (row - 1) * TILE + su);
            }
        }
    }
    __syncthreads();

    // ---- Marking (MODE 1): wave-parallel strip marking. Flag the root in
    // lp (bit 16) and seed the sparse global parent (pixel + root). ----
    if constexpr (MODE == 1) {
        int p = -1;
        bool mark = false;
        if      (wave == 0) { if (tr > 0)  { p = lane;                      mark = (rowmask_sh[0]    >> lane) & 1ULL; } }
        else if (wave == 3) { if (tr < 31) { p = (TILE - 1) * TILE + lane;  mark = (rowmask_sh[63]   >> lane) & 1ULL; } }
        else if (wave == 1) { if (tc > 0)  { p = lane * TILE;               mark = rowmask_sh[lane] & 1ULL; } }
        else                { if (tc < 31) { p = lane * TILE + (TILE - 1);  mark = (rowmask_sh[lane] >> 63) & 1ULL; } }
        if (mark) {
            int v = find_root_m(lp, p);
            atomicOr(&lp[v], BFLAG);
            int rg = origin + (v >> 6) * W_DIM + (v & (TILE - 1));
            int pg = origin + (p >> 6) * W_DIM + (p & (TILE - 1));
            parent[pg] = rg;
            parent[rg] = rg;
        }
        __syncthreads();
    }

    // ---- Phase C: root walk (flag rides the final read), write labels
    // (MODE1) or parent (MODE0); flagged pixels append inline. ----
    #pragma unroll
    for (int j = 0; j < 4; ++j) {
        int s   = t + BLK * j;               // int4 slot in tile
        int row = s >> 4;
        int c4  = s & 15;
        int p0  = row * TILE + c4 * 4;
        int4 qv = reinterpret_cast<const int4*>(lp)[s];
        unsigned fgbits = (unsigned)((rowmask_sh[row] >> (c4 * 4)) & 0xFULL);
        int vr[4], qf[4];
        {
            int q = qv.x, v = q & PMASK, p = p0;
            if ((fgbits & 1u) && v != p) {
                int w = lp[v];
                while ((w & PMASK) != v) { v = w & PMASK; w = lp[v]; }
                q = w;
            }
            vr[0] = v; qf[0] = q;
        }
        {
            int q = qv.y, v = q & PMASK, p = p0 + 1;
            if ((fgbits & 2u) && v != p) {
                int w = lp[v];
                while ((w & PMASK) != v) { v = w & PMASK; w = lp[v]; }
                q = w;
            }
            vr[1] = v; qf[1] = q;
        }
        {
            int q = qv.z, v = q & PMASK, p = p0 + 2;
            if ((fgbits & 4u) && v != p) {
                int w = lp[v];
                while ((w & PMASK) != v) { v = w & PMASK; w = lp[v]; }
                q = w;
            }
            vr[2] = v; qf[2] = q;
        }
        {
            int q = qv.w, v = q & PMASK, p = p0 + 3;
            if ((fgbits & 8u) && v != p) {
                int w = lp[v];
                while ((w & PMASK) != v) { v = w & PMASK; w = lp[v]; }
                q = w;
            }
            vr[3] = v; qf[3] = q;
        }

        if constexpr (MODE == 0) {
            int4 o;
            o.x = (fgbits & 1u) ? origin + (vr[0] >> 6) * W_DIM + (vr[0] & (TILE - 1)) : -1;
            o.y = (fgbits & 2u) ? origin + (vr[1] >> 6) * W_DIM + (vr[1] & (TILE - 1)) : -1;
            o.z = (fgbits & 4u) ? origin + (vr[2] >> 6) * W_DIM + (vr[2] & (TILE - 1)) : -1;
            o.w = (fgbits & 8u) ? origin + (vr[3] >> 6) * W_DIM + (vr[3] & (TILE - 1)) : -1;
            reinterpret_cast<int4*>(parent + origin + row * W_DIM)[c4] = o;
        } else {
            float lab[4];
            #pragma unroll
            for (int k = 0; k < 4; ++k) {
                int v  = vr[k];
                bool fg = (fgbits >> k) & 1u;
                int rl = base_loc + ((v >> 6) << 11) + (v & (TILE - 1)); // root, local-in-image
                lab[k] = fg ? (float)(MULT - rl) : 0.0f;
                if (fg && (qf[k] & BFLAG)) {                 // border component
                    int off = atomicAdd(&cursor, 1);
                    int pg  = origin + row * W_DIM + c4 * 4 + k;
                    int g   = img_base + rl;
                    if (off < WCAP) slabs[tile * WCAP + off] = make_int2(pg, g);
                    else {
                        int oi = atomicAdd(ovf_cnt, 1);
                        if (oi < OVF_CAP) ovf[oi] = make_int2(pg, g);
                    }
                }
            }
            float4 o; o.x = lab[0]; o.y = lab[1]; o.z = lab[2]; o.w = lab[3];
            reinterpret_cast<float4*>(out + origin + row * W_DIM)[c4] = o;
        }
    }

    if constexpr (MODE == 1) {
        __syncthreads();
        if (t == 0) wl_cnt[tile] = (cursor < WCAP) ? cursor : WCAP;
    }
}

// Cross-tile merges; fg from bitmap, UF on sparse parent (endpoints are
// strip pixels -> initialized by cc_local's marking pass).
__global__ __launch_bounds__(BLK) void cc_border_bm(const unsigned long long* __restrict__ bm,
                                                    int* __restrict__ parent, int total) {
    int tid = blockIdx.x * blockDim.x + threadIdx.x;
    if (tid >= total) return;
    const int per_img = 2 * NB * W_DIM;
    int img = tid / per_img;
    int k   = tid % per_img;
    int base = img * MULT;
    const unsigned long long* b = bm + (size_t)img * H_DIM * (W_DIM / 64);
    auto FG = [&](int r, int c) -> bool {
        return (b[r * (W_DIM / 64) + (c >> 6)] >> (c & 63)) & 1ULL;
    };
    if (k < NB * W_DIM) {
        int r = TILE * (1 + k / W_DIM);
        int c = k % W_DIM;
        if (!FG(r, c)) return;
        int i  = base + r * W_DIM + c;
        int up = i - W_DIM;
        if (FG(r - 1, c))                      merge_uf(parent, i, up);
        if (c > 0         && FG(r - 1, c - 1)) merge_uf(parent, i, up - 1);
        if (c < W_DIM - 1 && FG(r - 1, c + 1)) merge_uf(parent, i, up + 1);
    } else {
        int m2 = k - NB * W_DIM;
        int c = TILE * (1 + m2 / H_DIM);
        int r = m2 % H_DIM;
        if (!FG(r, c)) return;
        int i   = base + r * W_DIM + c;
        int lft = i - 1;
        if (FG(r, c - 1))                      merge_uf(parent, i, lft);
        if (r > 0         && FG(r - 1, c - 1)) merge_uf(parent, i, lft - W_DIM);
        if (r < H_DIM - 1 && FG(r + 1, c - 1)) merge_uf(parent, i, lft + W_DIM);
    }
}

// Rewrite labels of border-component pixels whose root changed.
__global__ __launch_bounds__(BLK) void cc_fixup(const int2* __restrict__ slabs,
                                                const int* __restrict__ wl_cnt,
                                                const int2* __restrict__ ovf,
                                                const int* __restrict__ ovf_cnt,
                                                const int* __restrict__ parent,
                                                float* __restrict__ out, int ntiles) {
    int tid = blockIdx.x * blockDim.x + threadIdx.x;
    int slab_total = ntiles * WCAP;
    int2 e;
    if (tid < slab_total) {
        int tile = tid / WCAP, slot = tid - tile * WCAP;
        if (slot >= wl_cnt[tile]) return;
        e = slabs[tid];
    } else {
        int oi = tid - slab_total;
        int oc = *ovf_cnt; if (oc > OVF_CAP) oc = OVF_CAP;
        if (oi >= oc) return;
        e = ovf[oi];
    }
    int root = find_root(parent, e.y);
    if (root != e.y) out[e.x] = (float)(MULT - (root & (MULT - 1)));
}

// ---------------- legacy fallback kernels ----------------
__global__ __launch_bounds__(BLK) void cc_border(int* __restrict__ parent, int total) {
    int tid = blockIdx.x * blockDim.x + threadIdx.x;
    if (tid >= total) return;
    const int per_img = 2 * NB * W_DIM;
    int img = tid / per_img;
    int k   = tid % per_img;
    int base = img * MULT;
    if (k < NB * W_DIM) {
        int r = TILE * (1 + k / W_DIM);
        int c = k % W_DIM;
        int i = base + r * W_DIM + c;
        if (parent[i] < 0) return;
        int up = i - W_DIM;
        if (parent[up] >= 0)                      merge_uf(parent, i, up);
        if (c > 0         && parent[up - 1] >= 0) merge_uf(parent, i, up - 1);
        if (c < W_DIM - 1 && parent[up + 1] >= 0) merge_uf(parent, i, up + 1);
    } else {
        int m2 = k - NB * W_DIM;
        int c = TILE * (1 + m2 / H_DIM);
        int r = m2 % H_DIM;
        int i = base + r * W_DIM + c;
        if (parent[i] < 0) return;
        int lft = i - 1;
        if (parent[lft] >= 0)                            merge_uf(parent, i, lft);
        if (r > 0         && parent[lft - W_DIM] >= 0)   merge_uf(parent, i, lft - W_DIM);
        if (r < H_DIM - 1 && parent[lft + W_DIM] >= 0)   merge_uf(parent, i, lft + W_DIM);
    }
}

__global__ __launch_bounds__(BLK) void cc_write(const int* __restrict__ parent,
                                                float* __restrict__ out, int n4) {
    int i = blockIdx.x * blockDim.x + threadIdx.x;
    if (i >= n4) return;
    int4 p = reinterpret_cast<const int4*>(parent)[i];
    int a0 = (p.x >= 0) ? parent[p.x] : 0;
    int a1 = (p.y >= 0) ? parent[p.y] : 0;
    int a2 = (p.z >= 0) ? parent[p.z] : 0;
    int a3 = (p.w >= 0) ? parent[p.w] : 0;
    float4 o;
    { int v = p.x, w = a0; if (v >= 0) { while (w != v) { v = w; w = parent[v]; } }
      o.x = (p.x < 0) ? 0.f : (float)(MULT - (v & (MULT - 1))); }
    { int v = p.y, w = a1; if (v >= 0) { while (w != v) { v = w; w = parent[v]; } }
      o.y = (p.y < 0) ? 0.f : (float)(MULT - (v & (MULT - 1))); }
    { int v = p.z, w = a2; if (v >= 0) { while (w != v) { v = w; w = parent[v]; } }
      o.z = (p.z < 0) ? 0.f : (float)(MULT - (v & (MULT - 1))); }
    { int v = p.w, w = a3; if (v >= 0) { while (w != v) { v = w; w = parent[v]; } }
      o.w = (p.w < 0) ? 0.f : (float)(MULT - (v & (MULT - 1))); }
    reinterpret_cast<float4*>(out)[i] = o;
}

__global__ __launch_bounds__(BLK) void cc_flatten(int* __restrict__ parent, int n) {
    int i = blockIdx.x * blockDim.x + threadIdx.x;
    if (i >= n) return;
    int p = parent[i];
    if (p < 0 || p == i) return;
    int r = find_root(parent, p);
    if (r != p) parent[i] = r;
}

__global__ __launch_bounds__(BLK) void cc_final_inplace(int* __restrict__ parent, int n4) {
    int i = blockIdx.x * blockDim.x + threadIdx.x;
    if (i >= n4) return;
    int4 p = reinterpret_cast<const int4*>(parent)[i];
    float4 o;
    o.x = (p.x < 0) ? 0.f : (float)(MULT - (p.x & (MULT - 1)));
    o.y = (p.y < 0) ? 0.f : (float)(MULT - (p.y & (MULT - 1)));
    o.z = (p.z < 0) ? 0.f : (float)(MULT - (p.z & (MULT - 1)));
    o.w = (p.w < 0) ? 0.f : (float)(MULT - (p.w & (MULT - 1)));
    reinterpret_cast<float4*>(parent)[i] = o;
}

extern "C" void kernel_launch(void* const* d_in, const int* in_sizes, int n_in,
                              void* d_out, int out_size, void* d_ws, size_t ws_size,
                              hipStream_t stream) {
    const float* x = (const float*)d_in[0];
    const int n     = in_sizes[0];          // B*H*W
    const int n_img = n / MULT;
    const int n4    = n / 4;
    const int tiles = n_img * TILES_PER_IMG;
    const int border_threads = n_img * 2 * NB * W_DIM;

    // fused-path workspace layout
    size_t off_parent = 0;
    size_t off_bitmap = off_parent + (size_t)n * 4;
    size_t off_slabs  = off_bitmap + (size_t)n / 8;
    size_t off_cnt    = off_slabs  + (size_t)tiles * WCAP * 8;
    size_t off_ovf    = off_cnt    + (size_t)tiles * 4;
    size_t off_ovfcnt = off_ovf    + (size_t)OVF_CAP * 8;
    size_t need_fused = off_ovfcnt + 128;

    if (ws_size >= need_fused) {
        char* ws = (char*)d_ws;
        int*  parent  = (int*)(ws + off_parent);
        unsigned long long* bitmap = (unsigned long long*)(ws + off_bitmap);
        int2* slabs   = (int2*)(ws + off_slabs);
        int*  wl_cnt  = (int*)(ws + off_cnt);
        int2* ovf     = (int2*)(ws + off_ovf);
        int*  ovf_cnt = (int*)(ws + off_ovfcnt);
        float* out    = (float*)d_out;

        hipMemsetAsync(ovf_cnt, 0, sizeof(int), stream);
        cc_local<1><<<tiles, BLK, 0, stream>>>(x, parent, out, bitmap,
                                               slabs, wl_cnt, ovf, ovf_cnt);
        cc_border_bm<<<(border_threads + BLK - 1) / BLK, BLK, 0, stream>>>(bitmap, parent, border_threads);
        int fix_threads = tiles * WCAP + OVF_CAP;
        cc_fixup<<<(fix_threads + BLK - 1) / BLK, BLK, 0, stream>>>(slabs, wl_cnt, ovf, ovf_cnt,
                                                                    parent, out, tiles);
    } else {
        const bool use_ws = (ws_size >= (size_t)n * sizeof(int));
        int* parent = use_ws ? (int*)d_ws : (int*)d_out;
        cc_local<0><<<tiles, BLK, 0, stream>>>(x, parent, nullptr, nullptr,
                                               nullptr, nullptr, nullptr, nullptr);
        cc_border<<<(border_threads + BLK - 1) / BLK, BLK, 0, stream>>>(parent, border_threads);
        if (use_ws) {
            cc_write<<<(n4 + BLK - 1) / BLK, BLK, 0, stream>>>(parent, (float*)d_out, n4);
        } else {
            cc_flatten      <<<(n + BLK - 1) / BLK, BLK, 0, stream>>>(parent, n);
            cc_final_inplace<<<(n4 + BLK - 1) / BLK, BLK, 0, stream>>>(parent, n4);
        }
    }
}